// Round 6
// baseline (668.024 us; speedup 1.0000x reference)
//
#include <hip/hip_runtime.h>

// LSTM: T=512, B=4096, I=10, H=20. Gate order i,f,g,o (PyTorch).
// R8: weights live in LDS (one copy per block), not VGPRs.
//   R5-R7 forensics: allocator insists on a 64-VGPR allocation and
//   rematerializes the 62-reg weight set from GLOBAL every step
//   (~87 extra VALU insts/step of loads+addressing = the 3x gap).
//   Fix: make 64 regs the natural fit. Weights+bias staged once into
//   LDS (11.8KB/block, 144B padded rows -> 16B-aligned b128 reads,
//   rows spread over bank-quads by row%8). Per step each lane re-reads
//   its 2 rows as 8x ds_read_b128 with IMMEDIATE offsets: no addr
//   arith, no VMEM, ~2cy issue each. Bias rides free in pad word 10
//   (arrives with the third b128). Working set ~60 VGPRs -> no remat.
// Structure unchanged from R7 (proven correct): one batch per wave,
// lane = 2*j + s; s=0 owns {i_j,f_j}, s=1 owns {g_j,o_j}; full exec;
// DPP lane^1 gate gather; wave-synchronous hbuf h-exchange, no barriers
// in the loop. Block = 256 thr = 4 waves = 4 batches; grid = 1024.

#define T_STEPS 512
#define BATCH   4096
#define ISZ     10
#define HSZ     20
#define WPB     4            // waves (= batches) per block
#define NTHR    (WPB * 64)
#define WSTR    36           // floats per padded weight row (144B)
                             // [0..9]=Wih row, [10]=bias, [11]=pad, [12..31]=Whh row

typedef float v2f __attribute__((ext_vector_type(2)));
typedef float v4f __attribute__((ext_vector_type(4)));

static __device__ __forceinline__ v2f fma2(v2f a, v2f b, v2f c) {
    return __builtin_elementwise_fma(a, b, c);   // -> v_pk_fma_f32
}
static __device__ __forceinline__ v2f vlo(v4f v) { return (v2f){v.x, v.y}; }
static __device__ __forceinline__ v2f vhi(v4f v) { return (v2f){v.z, v.w}; }

#if defined(__has_builtin)
#if __has_builtin(__builtin_amdgcn_exp2f)
#define FAST_EXP2(x) __builtin_amdgcn_exp2f(x)
#endif
#if __has_builtin(__builtin_amdgcn_rcpf)
#define FAST_RCP(x) __builtin_amdgcn_rcpf(x)
#endif
#endif
#ifndef FAST_EXP2
#define FAST_EXP2(x) exp2f(x)
#endif
#ifndef FAST_RCP
#define FAST_RCP(x) (1.0f/(x))
#endif

// lane^1 partner swap via DPP quad_perm [1,0,3,2] -- 2-cycle VALU op.
__device__ __forceinline__ float dpp_xor1(float v) {
    return __int_as_float(__builtin_amdgcn_update_dpp(
        0, __float_as_int(v), 0xB1, 0xF, 0xF, true));
}

__global__ __launch_bounds__(NTHR) void lstm_fused_kernel(
    const float* __restrict__ x,    // [T, B, I]
    const float* __restrict__ h0,   // [B, H]
    const float* __restrict__ c0,   // [B, H]
    const float* __restrict__ Wih,  // [4H, I]
    const float* __restrict__ Whh,  // [4H, H]
    const float* __restrict__ bih,  // [4H]
    const float* __restrict__ bhh,  // [4H]
    float* __restrict__ out)        // [T*B*H] ++ [B*H] ++ [B*H]
{
    __shared__ __align__(16) float wlds[80 * WSTR];   // 11520 B
    __shared__ __align__(16) float hbuf[WPB][HSZ];    //   320 B

    const int tid = threadIdx.x;

    // ---- cooperative weight staging (once) ----
    for (int i = tid; i < 80 * ISZ; i += NTHR) {
        const int row = i / ISZ, k = i - row * ISZ;
        wlds[row * WSTR + k] = Wih[i];
    }
    for (int i = tid; i < 80 * HSZ; i += NTHR) {
        const int row = i / HSZ, k = i - row * HSZ;
        wlds[row * WSTR + 12 + k] = Whh[i];
    }
    for (int i = tid; i < 80; i += NTHR)
        wlds[i * WSTR + 10] = bih[i] + bhh[i];        // bias in pad word

    const int wid  = tid >> 6;
    const int lane = tid & 63;
    const int s    = lane & 1;              // 0:{i,f}  1:{g,o}
    const int jraw = lane >> 1;             // 0..31
    const bool live = (jraw < HSZ);
    const int j    = live ? jraw : (jraw - HSZ);   // lanes 40..63: benign dup
    const int gb   = blockIdx.x * WPB + wid;
    const bool st  = live && (s == 0);      // store-enable

    // slot0 activation: s0 -> sigmoid(i), s1 -> tanh(g).  slot1: sigmoid.
    const float B0c = s ? -2.8853900817779268f : -1.4426950408889634f;
    const float A0c = s ? 2.0f : 1.0f;
    const float C0c = s ? -1.0f : 0.0f;

    // per-lane LDS row bases (fixed; all in-loop reads use imm offsets)
    const float* wr0 = &wlds[((2 * s)     * HSZ + j) * WSTR];
    const float* wr1 = &wlds[((2 * s + 1) * HSZ + j) * WSTR];

    float c = c0[(size_t)gb * HSZ + j];
    if (st) hbuf[wid][j] = h0[(size_t)gb * HSZ + j];

    __syncthreads();   // weights staged + h init visible to all waves

    const float* xrow = x + (size_t)gb * ISZ;   // wave-uniform
    float* outp = out + (size_t)gb * HSZ + j;

    // x prefetch, 2 deep (refill at t loads x[t+2]); broadcast 40B loads
    v2f nxA[5], nxB[5];
    {
        const v2f* x0p = (const v2f*)(xrow);
        const v2f* x1p = (const v2f*)(xrow + (size_t)BATCH * ISZ);
#pragma unroll
        for (int q = 0; q < 5; ++q) { nxA[q] = x0p[q]; nxB[q] = x1p[q]; }
    }

    float hn = 0.0f;

#define STEP(NX, TI)                                                          \
    {                                                                         \
        /* 1) weight rows: 16x ds_read_b128, imm offsets, no addr arith */    \
        const v4f* W0 = (const v4f*)wr0;                                      \
        const v4f* W1 = (const v4f*)wr1;                                      \
        v4f wq0[8], wq1[8];                                                   \
        _Pragma("unroll")                                                     \
        for (int m = 0; m < 8; ++m) { wq0[m] = W0[m]; wq1[m] = W1[m]; }       \
        /* 2) h broadcast read (same 80B for whole wave -> free) */           \
        const v4f* hq = (const v4f*)(&hbuf[wid][0]);                          \
        v4f h4[5];                                                            \
        _Pragma("unroll")                                                     \
        for (int m = 0; m < 5; ++m) h4[m] = hq[m];                            \
        /* 3) x-part MACs; bias arrives as wq[2].z */                         \
        v2f a0 = {wq0[2].z, 0.0f}, a1 = {wq1[2].z, 0.0f};                     \
        a0 = fma2(vlo(wq0[0]), NX[0], a0); a1 = fma2(vlo(wq1[0]), NX[0], a1); \
        a0 = fma2(vhi(wq0[0]), NX[1], a0); a1 = fma2(vhi(wq1[0]), NX[1], a1); \
        a0 = fma2(vlo(wq0[1]), NX[2], a0); a1 = fma2(vlo(wq1[1]), NX[2], a1); \
        a0 = fma2(vhi(wq0[1]), NX[3], a0); a1 = fma2(vhi(wq1[1]), NX[3], a1); \
        a0 = fma2(vlo(wq0[2]), NX[4], a0); a1 = fma2(vlo(wq1[2]), NX[4], a1); \
        /* 4) refill this x slot with x[t+2] (clamped at tail) */             \
        {                                                                     \
            int tp = (TI) + 2; if (tp > T_STEPS - 1) tp = T_STEPS - 1;        \
            const v2f* xp = (const v2f*)(xrow + (size_t)tp * (BATCH * ISZ));  \
            _Pragma("unroll")                                                 \
            for (int q = 0; q < 5; ++q) NX[q] = xp[q];                        \
        }                                                                     \
        /* 5) h-part MACs (packed) */                                         \
        _Pragma("unroll")                                                     \
        for (int m = 0; m < 5; ++m) {                                         \
            a0 = fma2(vlo(wq0[3 + m]), vlo(h4[m]), a0);                       \
            a0 = fma2(vhi(wq0[3 + m]), vhi(h4[m]), a0);                       \
            a1 = fma2(vlo(wq1[3 + m]), vlo(h4[m]), a1);                       \
            a1 = fma2(vhi(wq1[3 + m]), vhi(h4[m]), a1);                       \
        }                                                                     \
        const float g0 = a0.x + a0.y;                                         \
        const float g1 = a1.x + a1.y;                                         \
        /* 6) own activations: s0 {sig(i), sig(f)}, s1 {tanh(g), sig(o)} */   \
        const float act0 = A0c * FAST_RCP(1.0f + FAST_EXP2(g0 * B0c)) + C0c;  \
        const float act1 = FAST_RCP(1.0f +                                    \
                           FAST_EXP2(g1 * -1.4426950408889634f));             \
        /* 7) partner gather: two independent DPP lane^1 swaps (VALU) */      \
        const float p0 = dpp_xor1(act0);   /* s0 gets tanh(g) */              \
        const float p1 = dpp_xor1(act1);   /* s0 gets sig(o)  */              \
        /* 8) c/h update -- valid on s==0, bounded junk elsewhere */          \
        c = __builtin_fmaf(act1, c, act0 * p0);                               \
        const float th = 2.0f * FAST_RCP(1.0f +                               \
                         FAST_EXP2(c * -2.8853900817779268f)) - 1.0f;         \
        hn = p1 * th;                                                         \
        if (st) {                                                             \
            hbuf[wid][j] = hn;                 /* wave-synchronous publish */ \
            outp[(size_t)(TI) * (BATCH * HSZ)] = hn;  /* 80B coalesced */     \
        }                                                                     \
        __builtin_amdgcn_wave_barrier();  /* order write(t) < read(t+1) */    \
    }

    for (int t = 0; t < T_STEPS; t += 2) {
        STEP(nxA, t)
        STEP(nxB, t + 1)
    }
#undef STEP

    if (st) {
        const size_t tail = (size_t)T_STEPS * BATCH * HSZ;
        out[tail + (size_t)gb * HSZ + j] = hn;
        out[tail + (size_t)BATCH * HSZ + (size_t)gb * HSZ + j] = c;
    }
}

extern "C" void kernel_launch(void* const* d_in, const int* in_sizes, int n_in,
                              void* d_out, int out_size, void* d_ws, size_t ws_size,
                              hipStream_t stream) {
    const float* x   = (const float*)d_in[0];
    const float* h0  = (const float*)d_in[1];
    const float* c0  = (const float*)d_in[2];
    const float* Wih = (const float*)d_in[3];
    const float* Whh = (const float*)d_in[4];
    const float* bih = (const float*)d_in[5];
    const float* bhh = (const float*)d_in[6];
    float* out = (float*)d_out;

    const int nblk = BATCH / WPB;   // 1024 blocks = 4 per CU
    lstm_fused_kernel<<<nblk, NTHR, 0, stream>>>(x, h0, c0, Wih, Whh, bih, bhh, out);
}

// Round 7
// 578.590 us; speedup vs baseline: 1.1546x; 1.1546x over previous
//
#include <hip/hip_runtime.h>

// LSTM: T=512, B=4096, I=10, H=20. Gate order i,f,g,o (PyTorch).
// R9: x-projection hoisted OUT of the recurrence (chunked, LDS, wave-local).
//   R5-R8 forensics: allocator pins kernels at 64 VGPRs; the recurrence
//   with in-loop x-projection needs ~90 -> per-step remat from global
//   (R5-R7, ~3x inst bloat) or LDS weight re-reads (R8, LDS-pipe wall +
//   5-way conflicts). Fix: per CHUNK=16 steps, each wave first computes
//   xproj[t][gate] = Wih_row . x_t + bias for its OWN batch into its
//   private 5KB LDS buffer (all 64 lanes productive: rows lane, lane+64),
//   then runs 16 recurrence steps that read 8B of xproj + 80B of h from
//   LDS and do only the 20-wide h-MACs. Inner-loop live set ~60 VGPRs ->
//   fits the 64-reg allocation with NOTHING left to remat. No cross-wave
//   sharing -> zero __syncthreads; wave-synchronous DS ordering only.
// Structure from R6 (proven correct): one batch/wave, lane = 2*j + s;
// s=0 owns {i_j,f_j}, s=1 owns {g_j,o_j}; full exec, predicated stores;
// DPP lane^1 gate gather. Block = 256 = 4 waves = 4 batches; grid 1024.

#define T_STEPS 512
#define BATCH   4096
#define ISZ     10
#define HSZ     20
#define WPB     4            // waves (= batches) per block
#define NTHR    (WPB * 64)
#define CHUNK   16           // steps staged per burst; 512 % 16 == 0

typedef float v2f __attribute__((ext_vector_type(2)));
typedef float v4f __attribute__((ext_vector_type(4)));

static __device__ __forceinline__ v2f fma2(v2f a, v2f b, v2f c) {
    return __builtin_elementwise_fma(a, b, c);   // -> v_pk_fma_f32
}
static __device__ __forceinline__ v2f vlo(v4f v) { return (v2f){v.x, v.y}; }
static __device__ __forceinline__ v2f vhi(v4f v) { return (v2f){v.z, v.w}; }

#if defined(__has_builtin)
#if __has_builtin(__builtin_amdgcn_exp2f)
#define FAST_EXP2(x) __builtin_amdgcn_exp2f(x)
#endif
#if __has_builtin(__builtin_amdgcn_rcpf)
#define FAST_RCP(x) __builtin_amdgcn_rcpf(x)
#endif
#endif
#ifndef FAST_EXP2
#define FAST_EXP2(x) exp2f(x)
#endif
#ifndef FAST_RCP
#define FAST_RCP(x) (1.0f/(x))
#endif

// lane^1 partner swap via DPP quad_perm [1,0,3,2] -- 2-cycle VALU op.
__device__ __forceinline__ float dpp_xor1(float v) {
    return __int_as_float(__builtin_amdgcn_update_dpp(
        0, __float_as_int(v), 0xB1, 0xF, 0xF, true));
}

__global__ __launch_bounds__(NTHR, 4) void lstm_fused_kernel(
    const float* __restrict__ x,    // [T, B, I]
    const float* __restrict__ h0,   // [B, H]
    const float* __restrict__ c0,   // [B, H]
    const float* __restrict__ Wih,  // [4H, I]
    const float* __restrict__ Whh,  // [4H, H]
    const float* __restrict__ bih,  // [4H]
    const float* __restrict__ bhh,  // [4H]
    float* __restrict__ out)        // [T*B*H] ++ [B*H] ++ [B*H]
{
    // per-wave xproj chunk: [CHUNK][80] floats, slot = j*4 + gate
    __shared__ __align__(16) float xp[WPB][CHUNK * 80];   // 5120 B/wave
    __shared__ __align__(16) float hbuf[WPB][HSZ];        //   80 B/wave

    const int tid  = threadIdx.x;
    const int wid  = tid >> 6;
    const int lane = tid & 63;
    const int s    = lane & 1;              // 0:{i,f}  1:{g,o}
    const int jraw = lane >> 1;             // 0..31
    const bool live = (jraw < HSZ);
    const int j    = live ? jraw : (jraw - HSZ);   // lanes 40..63: benign dup
    const int gb   = blockIdx.x * WPB + wid;
    const bool st  = live && (s == 0);      // store-enable

    // slot0 activation: s0 -> sigmoid(i), s1 -> tanh(g).  slot1: sigmoid.
    const float B0c = s ? -2.8853900817779268f : -1.4426950408889634f;
    const float A0c = s ? 2.0f : 1.0f;
    const float C0c = s ? -1.0f : 0.0f;

    // recurrent weights: 2 rows/lane, 20 VGPRs (rows (2s)*H+j, (2s+1)*H+j)
    v2f wh0[10], wh1[10];
    {
        const v2f* p0 = (const v2f*)(Whh + ((2 * s)     * HSZ + j) * HSZ);
        const v2f* p1 = (const v2f*)(Whh + ((2 * s + 1) * HSZ + j) * HSZ);
#pragma unroll
        for (int q = 0; q < 10; ++q) { wh0[q] = p0[q]; wh1[q] = p1[q]; }
    }

    // staging assignment: lane handles Wih row ra=lane, and rb=lane+64
    // (lanes 0..15). row -> LDS slot: slot = (row%20)*4 + row/20.
    const int ra    = lane;
    const bool hasB = (lane < 4 * HSZ - 64);           // lane < 16
    const int rb    = hasB ? lane + 64 : 0;            // safe fallback row
    const int slotA = (ra % HSZ) * 4 + (ra / HSZ);
    const int slotB = (rb % HSZ) * 4 + (rb / HSZ);
    v2f wiA[5], wiB[5];
    {
        const v2f* pa = (const v2f*)(Wih + ra * ISZ);  // 40B rows, 8B aligned
        const v2f* pb = (const v2f*)(Wih + rb * ISZ);
#pragma unroll
        for (int q = 0; q < 5; ++q) { wiA[q] = pa[q]; wiB[q] = pb[q]; }
    }
    const float biasA = bih[ra] + bhh[ra];
    const float biasB = bih[rb] + bhh[rb];

    float c = c0[(size_t)gb * HSZ + j];
    if (st) hbuf[wid][j] = h0[(size_t)gb * HSZ + j];   // wave-sync init
    __builtin_amdgcn_wave_barrier();

    const float* xrow = x + (size_t)gb * ISZ;          // wave-uniform
    float* outcur = out + (size_t)gb * HSZ + j;        // advances per step

    float* xpw = &xp[wid][0];
    const float* xrd = &xp[wid][j * 4 + 2 * s];        // lane-fixed xp base

    float hn = 0.0f;

    for (int t0 = 0; t0 < T_STEPS; t0 += CHUNK) {
        // ---- stage xproj for this chunk (all 64 lanes productive) ----
#pragma unroll 4
        for (int u = 0; u < CHUNK; ++u) {
            const v2f* xg = (const v2f*)(xrow + (size_t)(t0 + u) * (BATCH * ISZ));
            v2f xv[5];
#pragma unroll
            for (int q = 0; q < 5; ++q) xv[q] = xg[q];
            v2f aA = {biasA, 0.0f}, aB = {biasB, 0.0f};
#pragma unroll
            for (int q = 0; q < 5; ++q) {
                aA = fma2(wiA[q], xv[q], aA);
                aB = fma2(wiB[q], xv[q], aB);
            }
            xpw[u * 80 + slotA] = aA.x + aA.y;     // 2-way bank alias: free
            if (hasB) xpw[u * 80 + slotB] = aB.x + aB.y;
        }
        __builtin_amdgcn_wave_barrier();   // stage writes before reads

        // ---- 16 recurrence steps (fully unrolled -> imm LDS offsets) ----
#pragma unroll
        for (int u = 0; u < CHUNK; ++u) {
            // xproj pair for this lane's two gates: one ds_read_b64
            const v2f xg = *(const v2f*)(xrd + u * 80);
            // h broadcast read: whole wave reads same 80B -> conflict-free
            const v4f* hq = (const v4f*)(&hbuf[wid][0]);
            v4f h4[5];
#pragma unroll
            for (int m = 0; m < 5; ++m) h4[m] = hq[m];
            // h-part MACs (packed), seeded by xproj
            v2f a0 = {xg.x, 0.0f}, a1 = {xg.y, 0.0f};
#pragma unroll
            for (int m = 0; m < 5; ++m) {
                a0 = fma2(wh0[2 * m],     vlo(h4[m]), a0);
                a0 = fma2(wh0[2 * m + 1], vhi(h4[m]), a0);
                a1 = fma2(wh1[2 * m],     vlo(h4[m]), a1);
                a1 = fma2(wh1[2 * m + 1], vhi(h4[m]), a1);
            }
            const float g0 = a0.x + a0.y;
            const float g1 = a1.x + a1.y;
            // own activations: s0 {sig(i), sig(f)}, s1 {tanh(g), sig(o)}
            const float act0 = A0c * FAST_RCP(1.0f + FAST_EXP2(g0 * B0c)) + C0c;
            const float act1 = FAST_RCP(1.0f +
                               FAST_EXP2(g1 * -1.4426950408889634f));
            // partner gather: two independent DPP lane^1 swaps (VALU)
            const float p0 = dpp_xor1(act0);   // s0 gets tanh(g)
            const float p1 = dpp_xor1(act1);   // s0 gets sig(o)
            // c/h update -- valid on s==0, bounded junk elsewhere
            c = __builtin_fmaf(act1, c, act0 * p0);
            const float th = 2.0f * FAST_RCP(1.0f +
                             FAST_EXP2(c * -2.8853900817779268f)) - 1.0f;
            hn = p1 * th;
            if (st) {
                hbuf[wid][j] = hn;                 // wave-synchronous publish
                *outcur = hn;                      // 80B coalesced per wave
            }
            outcur += (size_t)BATCH * HSZ;         // uniform pointer advance
            __builtin_amdgcn_wave_barrier();       // write(t) < read(t+1)
        }
        __builtin_amdgcn_wave_barrier();   // chunk reads done before restage
    }

    if (st) {
        const size_t tail = (size_t)T_STEPS * BATCH * HSZ;
        out[tail + (size_t)gb * HSZ + j] = hn;
        out[tail + (size_t)BATCH * HSZ + (size_t)gb * HSZ + j] = c;
    }
}

extern "C" void kernel_launch(void* const* d_in, const int* in_sizes, int n_in,
                              void* d_out, int out_size, void* d_ws, size_t ws_size,
                              hipStream_t stream) {
    const float* x   = (const float*)d_in[0];
    const float* h0  = (const float*)d_in[1];
    const float* c0  = (const float*)d_in[2];
    const float* Wih = (const float*)d_in[3];
    const float* Whh = (const float*)d_in[4];
    const float* bih = (const float*)d_in[5];
    const float* bhh = (const float*)d_in[6];
    float* out = (float*)d_out;

    const int nblk = BATCH / WPB;   // 1024 blocks = 4 per CU
    lstm_fused_kernel<<<nblk, NTHR, 0, stream>>>(x, h0, c0, Wih, Whh, bih, bhh, out);
}

// Round 8
// 566.037 us; speedup vs baseline: 1.1802x; 1.0222x over previous
//
#include <hip/hip_runtime.h>

// LSTM: T=512, B=4096, I=10, H=20. Gate order i,f,g,o (PyTorch).
// R10: NO LDS in the recurrence -- h broadcast via v_readlane to SGPRs.
//   R5-R9 forensics: every multi-wave variant lost to R2 (288us) because
//   the per-step LDS h-exchange (ds_write -> barrier -> ds_read, ~120cy +
//   lgkmcnt entanglement with staging) sits inside the 512-step serial
//   chain; 4 waves/SIMD couldn't hide it (VALUBusy 45-56%).
//   Fix: one batch per wave, lane = 2*j + s (R6's proven gate math).
//   Lane 2j holds the true hn_j -> 20x v_readlane (register op, ~2cy,
//   no memory counters) broadcasts h into wave-uniform SGPRs; h-MACs are
//   v_pk_fma with SGPR-pair operand. Zero LDS, zero barriers, zero
//   lgkmcnt in the chain. x prefetch stays VMEM (PF=2 ring covers HBM
//   latency). 4096 one-wave blocks = 4 waves/SIMD, fully independent.
// lane roles: s=0 owns rows {i_j,f_j}, s=1 owns {g_j,o_j}; full exec;
// DPP lane^1 gate gather; stores predicated to s==0, j<20.

#define T_STEPS 512
#define BATCH   4096
#define ISZ     10
#define HSZ     20
#define NTHR    64

typedef float v2f __attribute__((ext_vector_type(2)));

static __device__ __forceinline__ v2f fma2(v2f a, v2f b, v2f c) {
    return __builtin_elementwise_fma(a, b, c);   // -> v_pk_fma_f32
}

#if defined(__has_builtin)
#if __has_builtin(__builtin_amdgcn_exp2f)
#define FAST_EXP2(x) __builtin_amdgcn_exp2f(x)
#endif
#if __has_builtin(__builtin_amdgcn_rcpf)
#define FAST_RCP(x) __builtin_amdgcn_rcpf(x)
#endif
#endif
#ifndef FAST_EXP2
#define FAST_EXP2(x) exp2f(x)
#endif
#ifndef FAST_RCP
#define FAST_RCP(x) (1.0f/(x))
#endif

// lane^1 partner swap via DPP quad_perm [1,0,3,2] -- 2-cycle VALU op.
__device__ __forceinline__ float dpp_xor1(float v) {
    return __int_as_float(__builtin_amdgcn_update_dpp(
        0, __float_as_int(v), 0xB1, 0xF, 0xF, true));
}

// broadcast lane L's value to a wave-uniform (SGPR) float; ignores exec.
__device__ __forceinline__ float rdlane(float v, int l) {
    return __uint_as_float(__builtin_amdgcn_readlane(__float_as_uint(v), l));
}

__global__ __launch_bounds__(NTHR)
__attribute__((amdgpu_waves_per_eu(4, 4)))
void lstm_fused_kernel(
    const float* __restrict__ x,    // [T, B, I]
    const float* __restrict__ h0,   // [B, H]
    const float* __restrict__ c0,   // [B, H]
    const float* __restrict__ Wih,  // [4H, I]
    const float* __restrict__ Whh,  // [4H, H]
    const float* __restrict__ bih,  // [4H]
    const float* __restrict__ bhh,  // [4H]
    float* __restrict__ out)        // [T*B*H] ++ [B*H] ++ [B*H]
{
    const int lane = threadIdx.x & 63;
    const int s    = lane & 1;              // 0:{i,f}  1:{g,o}
    const int jraw = lane >> 1;             // 0..31
    const bool live = (jraw < HSZ);
    const int j    = live ? jraw : (jraw - HSZ);   // lanes 40..63: benign dup
    const int gb   = blockIdx.x;            // one batch per (1-wave) block
    const bool st  = live && (s == 0);      // store-enable

    // slot0 activation: s0 -> sigmoid(i), s1 -> tanh(g).  slot1: sigmoid.
    const float B0c = s ? -2.8853900817779268f : -1.4426950408889634f;
    const float A0c = s ? 2.0f : 1.0f;
    const float C0c = s ? -1.0f : 0.0f;

    // this lane's two gate rows: row_k = (2s+k)*HSZ + j
    v2f wi[2][5], wh[2][10];
    float bias[2];
#pragma unroll
    for (int k = 0; k < 2; ++k) {
        const int row = (2 * s + k) * HSZ + j;
        const v2f* wip = (const v2f*)(Wih + row * ISZ);   // 40B rows, 8B aligned
        const v2f* whp = (const v2f*)(Whh + row * HSZ);   // 80B rows
#pragma unroll
        for (int q = 0; q < 5; ++q)  wi[k][q] = wip[q];
#pragma unroll
        for (int q = 0; q < 10; ++q) wh[k][q] = whp[q];
        bias[k] = bih[row] + bhh[row];
    }

    float c  = c0[(size_t)gb * HSZ + j];
    float hn = h0[(size_t)gb * HSZ + j];    // lane 2j holds true h_j

    const float* xrow = x + (size_t)gb * ISZ;   // same addr across wave (VMEM bcast)
    float* outp = out + (size_t)gb * HSZ + j;

    // x prefetch, 2 deep (refill at t loads x[t+2]); broadcast 40B loads
    v2f nxA[5], nxB[5];
    {
        const v2f* x0p = (const v2f*)(xrow);
        const v2f* x1p = (const v2f*)(xrow + (size_t)BATCH * ISZ);
#pragma unroll
        for (int q = 0; q < 5; ++q) { nxA[q] = x0p[q]; nxB[q] = x1p[q]; }
    }

#define STEP(NX, TI)                                                          \
    {                                                                         \
        /* 1) h broadcast: 20 readlanes from lanes 0,2,..,38 -> SGPRs */      \
        float hs[HSZ];                                                        \
        _Pragma("unroll")                                                     \
        for (int k = 0; k < HSZ; ++k) hs[k] = rdlane(hn, 2 * k);              \
        /* 2) x-part MACs (no h dependency) */                                \
        v2f a0 = {bias[0], 0.0f}, a1 = {bias[1], 0.0f};                       \
        _Pragma("unroll")                                                     \
        for (int q = 0; q < 5; ++q) {                                         \
            a0 = fma2(wi[0][q], NX[q], a0);                                   \
            a1 = fma2(wi[1][q], NX[q], a1);                                   \
        }                                                                     \
        /* 3) refill this x slot with x[t+2] (clamped at tail, VMEM) */       \
        {                                                                     \
            int tp = (TI) + 2; if (tp > T_STEPS - 1) tp = T_STEPS - 1;        \
            const v2f* xp = (const v2f*)(xrow + (size_t)tp * (BATCH * ISZ));  \
            _Pragma("unroll")                                                 \
            for (int q = 0; q < 5; ++q) NX[q] = xp[q];                        \
        }                                                                     \
        /* 4) h-part MACs: pk_fma with uniform (SGPR-pair) h operand */       \
        _Pragma("unroll")                                                     \
        for (int m = 0; m < 10; ++m) {                                        \
            const v2f hp = {hs[2 * m], hs[2 * m + 1]};                        \
            a0 = fma2(wh[0][m], hp, a0);                                      \
            a1 = fma2(wh[1][m], hp, a1);                                      \
        }                                                                     \
        const float g0 = a0.x + a0.y;                                         \
        const float g1 = a1.x + a1.y;                                         \
        /* 5) own activations: s0 {sig(i), sig(f)}, s1 {tanh(g), sig(o)} */   \
        const float act0 = A0c * FAST_RCP(1.0f + FAST_EXP2(g0 * B0c)) + C0c;  \
        const float act1 = FAST_RCP(1.0f +                                    \
                           FAST_EXP2(g1 * -1.4426950408889634f));             \
        /* 6) partner gather: two independent DPP lane^1 swaps (VALU) */      \
        const float p0 = dpp_xor1(act0);   /* s0 gets tanh(g) */              \
        const float p1 = dpp_xor1(act1);   /* s0 gets sig(o)  */              \
        /* 7) c/h update -- valid on s==0, bounded junk elsewhere */          \
        c = __builtin_fmaf(act1, c, act0 * p0);                               \
        const float th = 2.0f * FAST_RCP(1.0f +                               \
                         FAST_EXP2(c * -2.8853900817779268f)) - 1.0f;         \
        hn = p1 * th;                                                         \
        if (st) outp[(size_t)(TI) * (BATCH * HSZ)] = hn;  /* 80B coalesced */ \
    }

    for (int t = 0; t < T_STEPS; t += 2) {
        STEP(nxA, t)
        STEP(nxB, t + 1)
    }
#undef STEP

    if (st) {
        const size_t tail = (size_t)T_STEPS * BATCH * HSZ;
        out[tail + (size_t)gb * HSZ + j] = hn;
        out[tail + (size_t)BATCH * HSZ + (size_t)gb * HSZ + j] = c;
    }
}

extern "C" void kernel_launch(void* const* d_in, const int* in_sizes, int n_in,
                              void* d_out, int out_size, void* d_ws, size_t ws_size,
                              hipStream_t stream) {
    const float* x   = (const float*)d_in[0];
    const float* h0  = (const float*)d_in[1];
    const float* c0  = (const float*)d_in[2];
    const float* Wih = (const float*)d_in[3];
    const float* Whh = (const float*)d_in[4];
    const float* bih = (const float*)d_in[5];
    const float* bhh = (const float*)d_in[6];
    float* out = (float*)d_out;

    lstm_fused_kernel<<<BATCH, NTHR, 0, stream>>>(x, h0, c0, Wih, Whh, bih, bhh, out);
}